// Round 1
// baseline (7215.204 us; speedup 1.0000x reference)
//
#include <hip/hip_runtime.h>
#include <math.h>

// ---- problem constants ----
#define T_    2048
#define D_    4096
#define NH_   32
#define QL_   1536     // Q_LORA
#define KVL_  512      // KV_LORA
#define ROPE_ 64       // QK_ROPE
#define NOPE_ 128      // QK_NOPE
#define HQK_  192      // QK_HEAD
#define HV_   128      // V_HEAD
#define KVD_  576      // KV_LORA + QK_ROPE

// ================= SGEMM (fp32, 128x128x8, 256 thr, 8x8 per thread) =================
// C[M x Ncols] = A[M x K] @ B[K x Ncols], all row-major.
// M % 128 == 0 and K % 8 == 0 assumed (true for all our shapes); Ncols bounds-checked.
__global__ __launch_bounds__(256) void sgemm_kernel(
    const float* __restrict__ A, const float* __restrict__ B, float* __restrict__ C,
    int M, int Ncols, int K) {
  const int BM = 128, BN = 128, BK = 8, TM = 8, TN = 8;
  __shared__ float As[BK][BM];
  __shared__ float Bs[BK][BN];
  int tid = threadIdx.x;
  int bm = blockIdx.y * BM;
  int bn = blockIdx.x * BN;
  int tx = tid & 15;      // 16 cols of threads
  int ty = tid >> 4;      // 16 rows of threads
  float acc[TM][TN];
  #pragma unroll
  for (int i = 0; i < TM; ++i)
    #pragma unroll
    for (int j = 0; j < TN; ++j) acc[i][j] = 0.0f;

  int arow = tid >> 1;            // 0..127
  int acol = (tid & 1) * 4;       // 0 or 4
  int brow = tid >> 5;            // 0..7
  int bcol = (tid & 31) * 4;      // 0..124

  for (int k0 = 0; k0 < K; k0 += BK) {
    float4 av = *(const float4*)(A + (size_t)(bm + arow) * K + k0 + acol);
    As[acol + 0][arow] = av.x;
    As[acol + 1][arow] = av.y;
    As[acol + 2][arow] = av.z;
    As[acol + 3][arow] = av.w;
    float4 bv = make_float4(0.f, 0.f, 0.f, 0.f);
    if (bn + bcol < Ncols)
      bv = *(const float4*)(B + (size_t)(k0 + brow) * Ncols + bn + bcol);
    *(float4*)&Bs[brow][bcol] = bv;
    __syncthreads();
    #pragma unroll
    for (int k = 0; k < BK; ++k) {
      float4 a0 = *(const float4*)&As[k][ty * TM];
      float4 a1 = *(const float4*)&As[k][ty * TM + 4];
      float4 b0 = *(const float4*)&Bs[k][tx * TN];
      float4 b1 = *(const float4*)&Bs[k][tx * TN + 4];
      float ra[8] = {a0.x, a0.y, a0.z, a0.w, a1.x, a1.y, a1.z, a1.w};
      float rb[8] = {b0.x, b0.y, b0.z, b0.w, b1.x, b1.y, b1.z, b1.w};
      #pragma unroll
      for (int i = 0; i < TM; ++i)
        #pragma unroll
        for (int j = 0; j < TN; ++j) acc[i][j] = fmaf(ra[i], rb[j], acc[i][j]);
    }
    __syncthreads();
  }
  #pragma unroll
  for (int i = 0; i < TM; ++i) {
    int row = bm + ty * TM + i;
    #pragma unroll
    for (int j = 0; j < TN; ++j) {
      int col = bn + tx * TN + j;
      if (col < Ncols) C[(size_t)row * Ncols + col] = acc[i][j];
    }
  }
}

// ================= RMSNorm over rows =================
// out[row][0..len) = in[row*stride + i] * rsqrt(mean(sq)+eps) * scale[i]
__global__ __launch_bounds__(256) void rmsnorm_kernel(
    const float* __restrict__ in, float* __restrict__ out,
    const float* __restrict__ scale, int len, int in_stride) {
  int row = blockIdx.x;
  const float* x = in + (size_t)row * in_stride;
  float* y = out + (size_t)row * len;
  float ss = 0.f;
  for (int i = threadIdx.x; i < len; i += 256) { float v = x[i]; ss += v * v; }
  __shared__ float red[4];
  #pragma unroll
  for (int o = 32; o > 0; o >>= 1) ss += __shfl_down(ss, o, 64);
  int wid = threadIdx.x >> 6, lane = threadIdx.x & 63;
  if (lane == 0) red[wid] = ss;
  __syncthreads();
  if (threadIdx.x == 0) {
    float t = red[0] + red[1] + red[2] + red[3];
    red[0] = 1.0f / sqrtf(t / (float)len + 1e-6f);
  }
  __syncthreads();
  float r = red[0];
  for (int i = threadIdx.x; i < len; i += 256) y[i] = x[i] * r * scale[i];
}

// ================= RoPE table =================
struct InvFreq { float f[32]; };
__global__ __launch_bounds__(256) void rope_table_kernel(
    const int* __restrict__ pos, float* __restrict__ cosT, float* __restrict__ sinT,
    InvFreq invf) {
  int idx = blockIdx.x * 256 + threadIdx.x;
  if (idx >= T_ * 32) return;
  int t = idx >> 5, i = idx & 31;
  float fr = (float)pos[t] * invf.f[i];
  cosT[idx] = cosf(fr);
  sinT[idx] = sinf(fr);
}

// ================= RoPE on q (in place, dims 128..191 of each head) =================
__global__ __launch_bounds__(256) void rope_q_kernel(
    float* __restrict__ q, const float* __restrict__ cosT, const float* __restrict__ sinT) {
  int idx = blockIdx.x * 256 + threadIdx.x;   // T*NH*32
  if (idx >= T_ * NH_ * 32) return;
  int i = idx & 31;
  int tn = idx >> 5;
  int t = tn >> 5;                            // NH_ == 32
  float* b = q + (size_t)tn * HQK_ + NOPE_;
  float x1 = b[i], x2 = b[i + 32];
  float c = cosT[t * 32 + i], s = sinT[t * 32 + i];
  b[i] = x1 * c - x2 * s;
  b[i + 32] = x1 * s + x2 * c;
}

// ================= RoPE on k (kv_sa cols 512..575 -> k_rope[T][64]) =================
__global__ __launch_bounds__(256) void rope_k_kernel(
    const float* __restrict__ kv_sa, const float* __restrict__ cosT,
    const float* __restrict__ sinT, float* __restrict__ k_rope) {
  int idx = blockIdx.x * 256 + threadIdx.x;   // T*32
  if (idx >= T_ * 32) return;
  int t = idx >> 5, i = idx & 31;
  const float* b = kv_sa + (size_t)t * KVD_ + KVL_;
  float x1 = b[i], x2 = b[i + 32];
  float c = cosT[idx], s = sinT[idx];
  k_rope[t * 64 + i]      = x1 * c - x2 * s;
  k_rope[t * 64 + i + 32] = x1 * s + x2 * c;
}

// ================= Attention (causal, online softmax) =================
// Block: 256 thr = 4 waves; handles head n and 16 q rows. Each wave owns 4 rows.
// s-tiles of 64; lane <-> s within tile.
#define STILE 64
__global__ __launch_bounds__(256) void attn_kernel(
    const float* __restrict__ q_tnh, const float* __restrict__ kv_nope,
    const float* __restrict__ k_rope, float* __restrict__ attn_out, float sm_scale) {
  __shared__ float qs[HQK_][16];     // [h][r]
  __shared__ float Ks[HQK_][STILE];  // [h][s]
  __shared__ float Vs[STILE][HV_];   // [s][h]
  __shared__ float ps[4][STILE][4];  // per wave: [s][r]
  int tid = threadIdx.x;
  int lane = tid & 63;
  int w = tid >> 6;
  int n = blockIdx.y;
  int t0 = blockIdx.x * 16;

  for (int idx = tid; idx < 16 * HQK_; idx += 256) {
    int h = idx >> 4, r = idx & 15;
    qs[h][r] = q_tnh[((size_t)(t0 + r) * NH_ + n) * HQK_ + h];
  }

  int r_base = w * 4;
  int tmax_wave = t0 + r_base + 3;
  float m[4], l[4], o0[4], o1[4];
  #pragma unroll
  for (int r = 0; r < 4; ++r) { m[r] = -1e30f; l[r] = 0.f; o0[r] = 0.f; o1[r] = 0.f; }

  int nt = (t0 + 15) / STILE + 1;
  for (int st = 0; st < nt; ++st) {
    int s0 = st * STILE;
    __syncthreads();   // protect Ks/Vs from previous iteration's readers (and qs first time)
    for (int idx = tid; idx < HQK_ * STILE; idx += 256) {
      int s = idx / HQK_, h = idx % HQK_;    // consecutive tid -> consecutive h (coalesced)
      float v;
      if (h < NOPE_) v = kv_nope[((size_t)(s0 + s) * NH_ + n) * 256 + h];
      else           v = k_rope[(size_t)(s0 + s) * ROPE_ + (h - NOPE_)];
      Ks[h][s] = v;
    }
    for (int idx = tid; idx < STILE * HV_; idx += 256) {
      int s = idx >> 7, h = idx & 127;
      Vs[s][h] = kv_nope[((size_t)(s0 + s) * NH_ + n) * 256 + NOPE_ + h];
    }
    __syncthreads();
    if (s0 <= tmax_wave) {
      float sc[4] = {0.f, 0.f, 0.f, 0.f};
      #pragma unroll 4
      for (int h = 0; h < HQK_; ++h) {
        float kv = Ks[h][lane];
        float4 qv = *(const float4*)&qs[h][r_base];
        sc[0] = fmaf(qv.x, kv, sc[0]);
        sc[1] = fmaf(qv.y, kv, sc[1]);
        sc[2] = fmaf(qv.z, kv, sc[2]);
        sc[3] = fmaf(qv.w, kv, sc[3]);
      }
      float p[4];
      #pragma unroll
      for (int r = 0; r < 4; ++r) {
        int tg = t0 + r_base + r;
        float sv = (s0 + lane <= tg) ? sc[r] * sm_scale : -1e30f;
        float mx = sv;
        #pragma unroll
        for (int off = 32; off > 0; off >>= 1) mx = fmaxf(mx, __shfl_xor(mx, off, 64));
        float mnew = fmaxf(m[r], mx);
        float corr = __expf(m[r] - mnew);
        float pv = __expf(sv - mnew);
        float sum = pv;
        #pragma unroll
        for (int off = 32; off > 0; off >>= 1) sum += __shfl_xor(sum, off, 64);
        l[r] = l[r] * corr + sum;
        o0[r] *= corr; o1[r] *= corr;
        m[r] = mnew;
        p[r] = pv;
      }
      *(float4*)&ps[w][lane][0] = make_float4(p[0], p[1], p[2], p[3]);
      // same-wave LDS RAW: compiler orders via lgkmcnt (may-alias shared accesses)
      for (int s = 0; s < STILE; ++s) {
        float4 pb = *(const float4*)&ps[w][s][0];
        float2 v = *(const float2*)&Vs[s][2 * lane];
        o0[0] = fmaf(pb.x, v.x, o0[0]); o1[0] = fmaf(pb.x, v.y, o1[0]);
        o0[1] = fmaf(pb.y, v.x, o0[1]); o1[1] = fmaf(pb.y, v.y, o1[1]);
        o0[2] = fmaf(pb.z, v.x, o0[2]); o1[2] = fmaf(pb.z, v.y, o1[2]);
        o0[3] = fmaf(pb.w, v.x, o0[3]); o1[3] = fmaf(pb.w, v.y, o1[3]);
      }
    }
  }
  #pragma unroll
  for (int r = 0; r < 4; ++r) {
    int tg = t0 + r_base + r;
    float inv = 1.0f / l[r];
    float* dst = attn_out + ((size_t)tg * NH_ + n) * HV_ + 2 * lane;
    dst[0] = o0[r] * inv;
    dst[1] = o1[r] * inv;
  }
}

// ================= host side =================
static void compute_inv_freq(float* out) {
  const double theta = 10000.0, factor = 40.0;
  const double PI = 3.14159265358979323846;
  const int rot = ROPE_;
  double low_d  = rot * log(4096.0 / (32.0 * 2.0 * PI)) / (2.0 * log(theta));
  double high_d = rot * log(4096.0 / ( 1.0 * 2.0 * PI)) / (2.0 * log(theta));
  double low = floor(low_d);  if (low < 0) low = 0;
  double high = ceil(high_d); if (high > rot - 1) high = rot - 1;
  for (int i = 0; i < 32; ++i) {
    double pf = pow(theta, (2.0 * i) / (double)rot);
    double inv_extra = 1.0 / pf;
    double inv_inter = 1.0 / (factor * pf);
    double ramp = ((double)i - low) / fmax(high - low, 0.001);
    ramp = fmin(fmax(ramp, 0.0), 1.0);
    double mask = 1.0 - ramp;   // inv_freq = inter*(1-mask) + extra*mask
    out[i] = (float)(inv_inter * (1.0 - mask) + inv_extra * mask);
  }
}

extern "C" void kernel_launch(void* const* d_in, const int* in_sizes, int n_in,
                              void* d_out, int out_size, void* d_ws, size_t ws_size,
                              hipStream_t stream) {
  const float* x            = (const float*)d_in[0];
  const int*   positions    = (const int*)d_in[1];
  const float* w_q_down     = (const float*)d_in[2];
  const float* q_norm_scale = (const float*)d_in[3];
  const float* w_q_up       = (const float*)d_in[4];
  const float* w_kv_down    = (const float*)d_in[5];
  const float* kv_norm_scale= (const float*)d_in[6];
  const float* w_kv_up      = (const float*)d_in[7];
  const float* w_o          = (const float*)d_in[8];
  float* out = (float*)d_out;

  // workspace layout (floats)
  float* ws = (float*)d_ws;
  size_t off = 0;
  float* cosT    = ws + off; off += (size_t)T_ * 32;
  float* sinT    = ws + off; off += (size_t)T_ * 32;
  float* q_ta    = ws + off; off += (size_t)T_ * QL_;
  float* q_tnh   = ws + off; off += (size_t)T_ * NH_ * HQK_;
  float* kv_sa   = ws + off; off += (size_t)T_ * KVD_;
  float* kv_lat  = ws + off; off += (size_t)T_ * KVL_;
  float* k_rope  = ws + off; off += (size_t)T_ * ROPE_;
  float* kv_nope = ws + off; off += (size_t)T_ * NH_ * 256;
  float* attn_o  = ws + off; off += (size_t)T_ * NH_ * HV_;
  (void)ws_size; (void)n_in; (void)in_sizes; (void)out_size;

  InvFreq invf;
  compute_inv_freq(invf.f);
  double ym = 0.1 * log(40.0) + 1.0;
  float sm_scale = (float)(ym * ym / sqrt((double)HQK_));

  // 1. rope cos/sin table
  rope_table_kernel<<<(T_ * 32 + 255) / 256, 256, 0, stream>>>(positions, cosT, sinT, invf);
  // 2. q_pre = x @ w_q_down
  sgemm_kernel<<<dim3(QL_ / 128, T_ / 128), 256, 0, stream>>>(x, w_q_down, q_ta, T_, QL_, D_);
  // 3. rmsnorm q (in place)
  rmsnorm_kernel<<<T_, 256, 0, stream>>>(q_ta, q_ta, q_norm_scale, QL_, QL_);
  // 4. q_tnh = q_ta @ w_q_up
  sgemm_kernel<<<dim3(NH_ * HQK_ / 128, T_ / 128), 256, 0, stream>>>(q_ta, w_q_up, q_tnh, T_, NH_ * HQK_, QL_);
  // 5. rope on q
  rope_q_kernel<<<(T_ * NH_ * 32 + 255) / 256, 256, 0, stream>>>(q_tnh, cosT, sinT);
  // 6. kv_sa = x @ w_kv_down
  sgemm_kernel<<<dim3((KVD_ + 127) / 128, T_ / 128), 256, 0, stream>>>(x, w_kv_down, kv_sa, T_, KVD_, D_);
  // 7. rmsnorm kv (cols 0..511, stride 576 -> kv_lat)
  rmsnorm_kernel<<<T_, 256, 0, stream>>>(kv_sa, kv_lat, kv_norm_scale, KVL_, KVD_);
  // 8. rope on k
  rope_k_kernel<<<(T_ * 32 + 255) / 256, 256, 0, stream>>>(kv_sa, cosT, sinT, k_rope);
  // 9. kv_nope = kv_lat @ w_kv_up   -> [s][n][256] (128 k_nope + 128 v)
  sgemm_kernel<<<dim3(NH_ * 256 / 128, T_ / 128), 256, 0, stream>>>(kv_lat, w_kv_up, kv_nope, T_, NH_ * 256, KVL_);
  // 10. attention
  attn_kernel<<<dim3(T_ / 16, NH_), 256, 0, stream>>>(q_tnh, kv_nope, k_rope, attn_o, sm_scale);
  // 11. out = attn_o @ w_o
  sgemm_kernel<<<dim3(D_ / 128, T_ / 128), 256, 0, stream>>>(attn_o, w_o, out, T_, D_, NH_ * HV_);
}

// Round 2
// 3242.979 us; speedup vs baseline: 2.2249x; 2.2249x over previous
//
#include <hip/hip_runtime.h>
#include <math.h>

// ---- problem constants ----
#define T_    2048
#define D_    4096
#define NH_   32
#define QL_   1536     // Q_LORA
#define KVL_  512      // KV_LORA
#define ROPE_ 64       // QK_ROPE
#define NOPE_ 128      // QK_NOPE
#define HQK_  192      // QK_HEAD
#define HV_   128      // V_HEAD
#define KVD_  576      // KV_LORA + QK_ROPE

typedef __bf16 bf16x8 __attribute__((ext_vector_type(8)));
typedef __bf16 bf16x4 __attribute__((ext_vector_type(4)));
typedef float f32x4 __attribute__((ext_vector_type(4)));

// ================= SGEMM (fp32, 128x128x8, 256 thr, 8x8 per thread) =================
__global__ __launch_bounds__(256) void sgemm_kernel(
    const float* __restrict__ A, const float* __restrict__ B, float* __restrict__ C,
    int M, int Ncols, int K) {
  const int BM = 128, BN = 128, BK = 8, TM = 8, TN = 8;
  __shared__ float As[BK][BM];
  __shared__ float Bs[BK][BN];
  int tid = threadIdx.x;
  int bm = blockIdx.y * BM;
  int bn = blockIdx.x * BN;
  int tx = tid & 15;
  int ty = tid >> 4;
  float acc[TM][TN];
  #pragma unroll
  for (int i = 0; i < TM; ++i)
    #pragma unroll
    for (int j = 0; j < TN; ++j) acc[i][j] = 0.0f;

  int arow = tid >> 1;
  int acol = (tid & 1) * 4;
  int brow = tid >> 5;
  int bcol = (tid & 31) * 4;

  for (int k0 = 0; k0 < K; k0 += BK) {
    float4 av = *(const float4*)(A + (size_t)(bm + arow) * K + k0 + acol);
    As[acol + 0][arow] = av.x;
    As[acol + 1][arow] = av.y;
    As[acol + 2][arow] = av.z;
    As[acol + 3][arow] = av.w;
    float4 bv = make_float4(0.f, 0.f, 0.f, 0.f);
    if (bn + bcol < Ncols)
      bv = *(const float4*)(B + (size_t)(k0 + brow) * Ncols + bn + bcol);
    *(float4*)&Bs[brow][bcol] = bv;
    __syncthreads();
    #pragma unroll
    for (int k = 0; k < BK; ++k) {
      float4 a0 = *(const float4*)&As[k][ty * TM];
      float4 a1 = *(const float4*)&As[k][ty * TM + 4];
      float4 b0 = *(const float4*)&Bs[k][tx * TN];
      float4 b1 = *(const float4*)&Bs[k][tx * TN + 4];
      float ra[8] = {a0.x, a0.y, a0.z, a0.w, a1.x, a1.y, a1.z, a1.w};
      float rb[8] = {b0.x, b0.y, b0.z, b0.w, b1.x, b1.y, b1.z, b1.w};
      #pragma unroll
      for (int i = 0; i < TM; ++i)
        #pragma unroll
        for (int j = 0; j < TN; ++j) acc[i][j] = fmaf(ra[i], rb[j], acc[i][j]);
    }
    __syncthreads();
  }
  #pragma unroll
  for (int i = 0; i < TM; ++i) {
    int row = bm + ty * TM + i;
    #pragma unroll
    for (int j = 0; j < TN; ++j) {
      int col = bn + tx * TN + j;
      if (col < Ncols) C[(size_t)row * Ncols + col] = acc[i][j];
    }
  }
}

// ================= RMSNorm over rows =================
__global__ __launch_bounds__(256) void rmsnorm_kernel(
    const float* __restrict__ in, float* __restrict__ out,
    const float* __restrict__ scale, int len, int in_stride) {
  int row = blockIdx.x;
  const float* x = in + (size_t)row * in_stride;
  float* y = out + (size_t)row * len;
  float ss = 0.f;
  for (int i = threadIdx.x; i < len; i += 256) { float v = x[i]; ss += v * v; }
  __shared__ float red[4];
  #pragma unroll
  for (int o = 32; o > 0; o >>= 1) ss += __shfl_down(ss, o, 64);
  int wid = threadIdx.x >> 6, lane = threadIdx.x & 63;
  if (lane == 0) red[wid] = ss;
  __syncthreads();
  if (threadIdx.x == 0) {
    float t = red[0] + red[1] + red[2] + red[3];
    red[0] = 1.0f / sqrtf(t / (float)len + 1e-6f);
  }
  __syncthreads();
  float r = red[0];
  for (int i = threadIdx.x; i < len; i += 256) y[i] = x[i] * r * scale[i];
}

// ================= RoPE table =================
struct InvFreq { float f[32]; };
__global__ __launch_bounds__(256) void rope_table_kernel(
    const int* __restrict__ pos, float* __restrict__ cosT, float* __restrict__ sinT,
    InvFreq invf) {
  int idx = blockIdx.x * 256 + threadIdx.x;
  if (idx >= T_ * 32) return;
  int t = idx >> 5, i = idx & 31;
  float fr = (float)pos[t] * invf.f[i];
  cosT[idx] = cosf(fr);
  sinT[idx] = sinf(fr);
}

// ================= RoPE on q (in place) =================
__global__ __launch_bounds__(256) void rope_q_kernel(
    float* __restrict__ q, const float* __restrict__ cosT, const float* __restrict__ sinT) {
  int idx = blockIdx.x * 256 + threadIdx.x;   // T*NH*32
  if (idx >= T_ * NH_ * 32) return;
  int i = idx & 31;
  int tn = idx >> 5;
  int t = tn >> 5;                            // NH_ == 32
  float* b = q + (size_t)tn * HQK_ + NOPE_;
  float x1 = b[i], x2 = b[i + 32];
  float c = cosT[t * 32 + i], s = sinT[t * 32 + i];
  b[i] = x1 * c - x2 * s;
  b[i + 32] = x1 * s + x2 * c;
}

// ================= RoPE on k =================
__global__ __launch_bounds__(256) void rope_k_kernel(
    const float* __restrict__ kv_sa, const float* __restrict__ cosT,
    const float* __restrict__ sinT, float* __restrict__ k_rope) {
  int idx = blockIdx.x * 256 + threadIdx.x;   // T*32
  if (idx >= T_ * 32) return;
  int t = idx >> 5, i = idx & 31;
  const float* b = kv_sa + (size_t)t * KVD_ + KVL_;
  float x1 = b[i], x2 = b[i + 32];
  float c = cosT[idx], s = sinT[idx];
  k_rope[t * 64 + i]      = x1 * c - x2 * s;
  k_rope[t * 64 + i + 32] = x1 * s + x2 * c;
}

// ================= V transpose prep: kv_nope[s][n][128+h] fp32 -> Vt[n][h][s] bf16 ===
__global__ __launch_bounds__(256) void prep_vt_kernel(
    const float* __restrict__ kv_nope, __bf16* __restrict__ Vt) {
  __shared__ __bf16 tile[64][130];   // stride 130 elems = 65 dwords: stride-4 rows spread banks
  int s0 = blockIdx.x * 64;
  int n = blockIdx.y;
  int tid = threadIdx.x;
  #pragma unroll
  for (int i = 0; i < 8; ++i) {
    int idx = tid + i * 256;          // 2048 tasks: 64 s x 32 h4
    int s = idx >> 5, h4 = (idx & 31) * 4;
    float4 v = *(const float4*)(kv_nope + ((size_t)(s0 + s) * NH_ + n) * 256 + NOPE_ + h4);
    tile[s][h4 + 0] = (__bf16)v.x; tile[s][h4 + 1] = (__bf16)v.y;
    tile[s][h4 + 2] = (__bf16)v.z; tile[s][h4 + 3] = (__bf16)v.w;
  }
  __syncthreads();
  #pragma unroll
  for (int i = 0; i < 8; ++i) {
    int idx = tid + i * 256;          // 2048 tasks: 128 h x 16 s4
    int h = idx >> 4, s4 = (idx & 15) * 4;
    bf16x4 v;
    v[0] = tile[s4 + 0][h]; v[1] = tile[s4 + 1][h];
    v[2] = tile[s4 + 2][h]; v[3] = tile[s4 + 3][h];
    *(bf16x4*)(Vt + ((size_t)n * HV_ + h) * T_ + s0 + s4) = v;
  }
}

// ================= MFMA flash attention =================
__global__ __launch_bounds__(256) void attn_mfma_kernel(
    const float* __restrict__ q_tnh, const float* __restrict__ kv_nope,
    const float* __restrict__ k_rope, const __bf16* __restrict__ Vt,
    float* __restrict__ attn_out, float sm_scale) {
  __shared__ __bf16 Ks[64 * 192];      // elem: s*192 + ((c^(s&7))<<3) + (h&7), c=h>>3
  __shared__ __bf16 Vs[128 * 64];      // elem: h*64  + ((c^(h&7))<<3) + (s&7), c=s>>3
  __shared__ __bf16 Ps[4][16 * 64];    // elem: r*64  + ((c^(r&7))<<3) + (sl&7), c=sl>>3
  const int tid = threadIdx.x;
  const int lane = tid & 63;
  const int w = tid >> 6;
  const int n = blockIdx.y;
  const int qt = gridDim.x - 1 - blockIdx.x;   // heaviest q-tiles dispatched first
  const int t0 = qt * 64;
  const int lg = lane >> 4;       // 0..3
  const int lj = lane & 15;       // 0..15

  // Q fragments, pre-scaled by sm_scale. A layout: row=lane%16, col=kk*32+lg*8+i.
  bf16x8 qf[6];
  {
    int t = t0 + w * 16 + lj;
    const float* qp = q_tnh + ((size_t)t * NH_ + n) * HQK_;
    #pragma unroll
    for (int kk = 0; kk < 6; ++kk) {
      int h0 = kk * 32 + lg * 8;
      bf16x8 v;
      #pragma unroll
      for (int i = 0; i < 8; ++i) v[i] = (__bf16)(qp[h0 + i] * sm_scale);
      qf[kk] = v;
    }
  }

  f32x4 O[8];
  #pragma unroll
  for (int nb = 0; nb < 8; ++nb) O[nb] = (f32x4){0.f, 0.f, 0.f, 0.f};
  float m_r[4], l_r[4];
  #pragma unroll
  for (int r = 0; r < 4; ++r) { m_r[r] = -1e30f; l_r[r] = 0.f; }

  for (int st = 0; st <= qt; ++st) {
    const int s0 = st * 64;
    __syncthreads();   // protect K/V LDS from previous iteration's readers
    // stage K: 64 s x 24 chunks of 8 bf16 (from fp32 kv_nope cols 0..127 + k_rope)
    #pragma unroll
    for (int i = 0; i < 6; ++i) {
      int task = tid + i * 256;
      int s = task / 24, c = task % 24;
      const float* src = (c < 16)
          ? (kv_nope + ((size_t)(s0 + s) * NH_ + n) * 256 + c * 8)
          : (k_rope + (size_t)(s0 + s) * ROPE_ + (c - 16) * 8);
      bf16x8 v;
      #pragma unroll
      for (int e = 0; e < 8; ++e) v[e] = (__bf16)src[e];
      *(bf16x8*)&Ks[s * 192 + ((c ^ (s & 7)) << 3)] = v;
    }
    // stage V^T: 128 h x 8 chunks of 8 bf16
    #pragma unroll
    for (int i = 0; i < 4; ++i) {
      int task = tid + i * 256;
      int h = task >> 3, cs = task & 7;
      bf16x8 v = *(const bf16x8*)(Vt + ((size_t)n * HV_ + h) * T_ + s0 + cs * 8);
      *(bf16x8*)&Vs[h * 64 + ((cs ^ (h & 7)) << 3)] = v;
    }
    __syncthreads();

    // QK^T: S[16 rows][64 cols] per wave
    f32x4 S[4];
    #pragma unroll
    for (int sb = 0; sb < 4; ++sb) {
      f32x4 acc = (f32x4){0.f, 0.f, 0.f, 0.f};
      int srow = sb * 16 + lj;
      #pragma unroll
      for (int kk = 0; kk < 6; ++kk) {
        int c = kk * 4 + lg;
        bf16x8 b = *(const bf16x8*)&Ks[srow * 192 + ((c ^ (srow & 7)) << 3)];
        acc = __builtin_amdgcn_mfma_f32_16x16x32_bf16(qf[kk], b, acc, 0, 0, 0);
      }
      S[sb] = acc;
    }
    // causal mask (diagonal tile only)
    if (st == qt) {
      #pragma unroll
      for (int sb = 0; sb < 4; ++sb)
        #pragma unroll
        for (int r = 0; r < 4; ++r) {
          int trel = w * 16 + lg * 4 + r;
          int srel = sb * 16 + lj;
          if (srel > trel) S[sb][r] = -1e30f;
        }
    }
    // online softmax; D layout: row=(lane>>4)*4+r, col=sb*16+(lane&15)
    #pragma unroll
    for (int r = 0; r < 4; ++r) {
      float mx = fmaxf(fmaxf(S[0][r], S[1][r]), fmaxf(S[2][r], S[3][r]));
      mx = fmaxf(mx, __shfl_xor(mx, 1));
      mx = fmaxf(mx, __shfl_xor(mx, 2));
      mx = fmaxf(mx, __shfl_xor(mx, 4));
      mx = fmaxf(mx, __shfl_xor(mx, 8));
      float mnew = fmaxf(m_r[r], mx);
      float corr = __expf(m_r[r] - mnew);
      m_r[r] = mnew;
      float psum = 0.f;
      #pragma unroll
      for (int sb = 0; sb < 4; ++sb) {
        float p = __expf(S[sb][r] - mnew);
        S[sb][r] = p;
        psum += p;
      }
      psum += __shfl_xor(psum, 1);
      psum += __shfl_xor(psum, 2);
      psum += __shfl_xor(psum, 4);
      psum += __shfl_xor(psum, 8);
      l_r[r] = l_r[r] * corr + psum;
      #pragma unroll
      for (int nb = 0; nb < 8; ++nb) O[nb][r] = O[nb][r] * corr;  // per-row rescale
    }
    // store P (bf16) to wave-local LDS, transposing D-layout -> A-layout
    #pragma unroll
    for (int sb = 0; sb < 4; ++sb) {
      int sl = sb * 16 + lj;
      int c = sl >> 3;
      #pragma unroll
      for (int r = 0; r < 4; ++r) {
        int rw = lg * 4 + r;
        Ps[w][rw * 64 + ((c ^ (rw & 7)) << 3) + (sl & 7)] = (__bf16)S[sb][r];
      }
    }
    // PV: O[16][128] += P[16][64] @ V[64][128]
    #pragma unroll
    for (int kk = 0; kk < 2; ++kk) {
      int ca = kk * 4 + lg;
      bf16x8 pa = *(const bf16x8*)&Ps[w][lj * 64 + ((ca ^ (lj & 7)) << 3)];
      #pragma unroll
      for (int nb = 0; nb < 8; ++nb) {
        int h = nb * 16 + lj;
        bf16x8 bv = *(const bf16x8*)&Vs[h * 64 + ((ca ^ (h & 7)) << 3)];
        O[nb] = __builtin_amdgcn_mfma_f32_16x16x32_bf16(pa, bv, O[nb], 0, 0, 0);
      }
    }
  }
  // epilogue
  #pragma unroll
  for (int r = 0; r < 4; ++r) {
    float inv = 1.0f / l_r[r];
    int t = t0 + w * 16 + lg * 4 + r;
    float* dst = attn_out + ((size_t)t * NH_ + n) * HV_;
    #pragma unroll
    for (int nb = 0; nb < 8; ++nb) dst[nb * 16 + lj] = O[nb][r] * inv;
  }
}

// ================= host side =================
static void compute_inv_freq(float* out) {
  const double theta = 10000.0, factor = 40.0;
  const double PI = 3.14159265358979323846;
  const int rot = ROPE_;
  double low_d  = rot * log(4096.0 / (32.0 * 2.0 * PI)) / (2.0 * log(theta));
  double high_d = rot * log(4096.0 / ( 1.0 * 2.0 * PI)) / (2.0 * log(theta));
  double low = floor(low_d);  if (low < 0) low = 0;
  double high = ceil(high_d); if (high > rot - 1) high = rot - 1;
  for (int i = 0; i < 32; ++i) {
    double pf = pow(theta, (2.0 * i) / (double)rot);
    double inv_extra = 1.0 / pf;
    double inv_inter = 1.0 / (factor * pf);
    double ramp = ((double)i - low) / fmax(high - low, 0.001);
    ramp = fmin(fmax(ramp, 0.0), 1.0);
    double mask = 1.0 - ramp;
    out[i] = (float)(inv_inter * (1.0 - mask) + inv_extra * mask);
  }
}

extern "C" void kernel_launch(void* const* d_in, const int* in_sizes, int n_in,
                              void* d_out, int out_size, void* d_ws, size_t ws_size,
                              hipStream_t stream) {
  const float* x            = (const float*)d_in[0];
  const int*   positions    = (const int*)d_in[1];
  const float* w_q_down     = (const float*)d_in[2];
  const float* q_norm_scale = (const float*)d_in[3];
  const float* w_q_up       = (const float*)d_in[4];
  const float* w_kv_down    = (const float*)d_in[5];
  const float* kv_norm_scale= (const float*)d_in[6];
  const float* w_kv_up      = (const float*)d_in[7];
  const float* w_o          = (const float*)d_in[8];
  float* out = (float*)d_out;

  // workspace layout (floats). Buffers dead before attention are FIRST so Vt
  // (bf16, 8.4M elems = 4.2M float-slots) can alias them (5.5M available).
  float* ws = (float*)d_ws;
  size_t off = 0;
  float* cosT    = ws + off; off += (size_t)T_ * 32;
  float* sinT    = ws + off; off += (size_t)T_ * 32;
  float* kv_sa   = ws + off; off += (size_t)T_ * KVD_;
  float* kv_lat  = ws + off; off += (size_t)T_ * KVL_;
  float* q_ta    = ws + off; off += (size_t)T_ * QL_;
  float* q_tnh   = ws + off; off += (size_t)T_ * NH_ * HQK_;
  float* k_rope  = ws + off; off += (size_t)T_ * ROPE_;
  float* kv_nope = ws + off; off += (size_t)T_ * NH_ * 256;
  float* attn_o  = ws + off; off += (size_t)T_ * NH_ * HV_;
  __bf16* Vt = (__bf16*)ws;
  (void)ws_size; (void)n_in; (void)in_sizes; (void)out_size;

  InvFreq invf;
  compute_inv_freq(invf.f);
  double ym = 0.1 * log(40.0) + 1.0;
  float sm_scale = (float)(ym * ym / sqrt((double)HQK_));

  rope_table_kernel<<<(T_ * 32 + 255) / 256, 256, 0, stream>>>(positions, cosT, sinT, invf);
  sgemm_kernel<<<dim3(QL_ / 128, T_ / 128), 256, 0, stream>>>(x, w_q_down, q_ta, T_, QL_, D_);
  rmsnorm_kernel<<<T_, 256, 0, stream>>>(q_ta, q_ta, q_norm_scale, QL_, QL_);
  sgemm_kernel<<<dim3(NH_ * HQK_ / 128, T_ / 128), 256, 0, stream>>>(q_ta, w_q_up, q_tnh, T_, NH_ * HQK_, QL_);
  rope_q_kernel<<<(T_ * NH_ * 32 + 255) / 256, 256, 0, stream>>>(q_tnh, cosT, sinT);
  sgemm_kernel<<<dim3((KVD_ + 127) / 128, T_ / 128), 256, 0, stream>>>(x, w_kv_down, kv_sa, T_, KVD_, D_);
  rmsnorm_kernel<<<T_, 256, 0, stream>>>(kv_sa, kv_lat, kv_norm_scale, KVL_, KVD_);
  rope_k_kernel<<<(T_ * 32 + 255) / 256, 256, 0, stream>>>(kv_sa, cosT, sinT, k_rope);
  sgemm_kernel<<<dim3(NH_ * 256 / 128, T_ / 128), 256, 0, stream>>>(kv_lat, w_kv_up, kv_nope, T_, NH_ * 256, KVL_);
  prep_vt_kernel<<<dim3(T_ / 64, NH_), 256, 0, stream>>>(kv_nope, Vt);
  attn_mfma_kernel<<<dim3(T_ / 64, NH_), 256, 0, stream>>>(q_tnh, kv_nope, k_rope, Vt, attn_o, sm_scale);
  sgemm_kernel<<<dim3(D_ / 128, T_ / 128), 256, 0, stream>>>(attn_o, w_o, out, T_, D_, NH_ * HV_);
}

// Round 3
// 585.269 us; speedup vs baseline: 12.3280x; 5.5410x over previous
//
#include <hip/hip_runtime.h>
#include <math.h>
#include <stdint.h>

// ---- problem constants ----
#define T_    2048
#define D_    4096
#define NH_   32
#define QL_   1536     // Q_LORA
#define KVL_  512      // KV_LORA
#define ROPE_ 64       // QK_ROPE
#define NOPE_ 128      // QK_NOPE
#define HQK_  192      // QK_HEAD
#define HV_   128      // V_HEAD
#define KVD_  576      // KV_LORA + QK_ROPE

typedef __bf16 bf16x8 __attribute__((ext_vector_type(8)));
typedef __bf16 bf16x4 __attribute__((ext_vector_type(4)));
typedef float f32x4 __attribute__((ext_vector_type(4)));

// async global->LDS, 16B per lane. LDS dest = wave-uniform base + lane*16.
__device__ __forceinline__ void gload_lds16(const __bf16* g, __bf16* l) {
  __builtin_amdgcn_global_load_lds(
      (const __attribute__((address_space(1))) void*)g,
      (__attribute__((address_space(3))) void*)l, 16, 0, 0);
}

// ============ bf16 MFMA GEMM: C[M][N] = A[M][K] * Bt[N][K]^T ============
// 128x128 tile, BK=32, 256 thr = 4 waves (2x2), each wave 64x64 = 4x4 frags.
// LDS tile [128 rows][32 k] bf16, row = 64B = 4 chunks of 16B; chunk XOR-swizzled
// with (row>>1)&3 (2-way bank alias = free). Swizzle applied on the GLOBAL source
// (global_load_lds dest is lane-linear) and on the ds_read side.
template <typename OutT>
__global__ __launch_bounds__(256, 3) void mfma_gemm_kernel(
    const __bf16* __restrict__ A, const __bf16* __restrict__ Bt,
    OutT* __restrict__ C, int M, int Ncols, int K) {
  __shared__ __bf16 As[128 * 32];
  __shared__ __bf16 Bs[128 * 32];
  const int tid = threadIdx.x;
  const int lane = tid & 63;
  const int w = tid >> 6;
  const int wm = w >> 1, wn = w & 1;
  const int lg = lane >> 4, lj = lane & 15;
  const int bm = blockIdx.y * 128;
  const int bn = blockIdx.x * 128;

  // staging: per-lane global src (pre-swizzled chunk), wave-uniform LDS dest
  const int sr = lane >> 2;    // row within 16-row wave slice
  const int sc = lane & 3;     // linear chunk
  const __bf16* ga[2]; const __bf16* gb[2];
  __bf16* la[2]; __bf16* lb[2];
  #pragma unroll
  for (int h = 0; h < 2; ++h) {
    int r = h * 64 + w * 16 + sr;           // tile row
    int cg = sc ^ ((r >> 1) & 3);           // global chunk for linear slot sc
    ga[h] = A  + (size_t)(bm + r) * K + cg * 8;
    gb[h] = Bt + (size_t)(bn + r) * K + cg * 8;
    la[h] = &As[(h * 64 + w * 16) * 32];
    lb[h] = &Bs[(h * 64 + w * 16) * 32];
  }

  // fragment read offsets (loop-invariant, swizzled)
  int roa[4], rob[4];
  #pragma unroll
  for (int i = 0; i < 4; ++i) {
    int ra_ = wm * 64 + i * 16 + lj;
    roa[i] = ra_ * 32 + ((lg ^ ((ra_ >> 1) & 3)) << 3);
    int rb_ = wn * 64 + i * 16 + lj;
    rob[i] = rb_ * 32 + ((lg ^ ((rb_ >> 1) & 3)) << 3);
  }

  f32x4 acc[4][4];
  #pragma unroll
  for (int mi = 0; mi < 4; ++mi)
    #pragma unroll
    for (int ni = 0; ni < 4; ++ni) acc[mi][ni] = (f32x4){0.f, 0.f, 0.f, 0.f};

  for (int k0 = 0; k0 < K; k0 += 32) {
    __syncthreads();                       // readers of previous tile done
    #pragma unroll
    for (int h = 0; h < 2; ++h) {
      gload_lds16(ga[h] + k0, la[h]);
      gload_lds16(gb[h] + k0, lb[h]);
    }
    __syncthreads();                       // vmcnt(0) drain inserted by compiler
    bf16x8 af[4], bfr[4];
    #pragma unroll
    for (int i = 0; i < 4; ++i) af[i]  = *(const bf16x8*)&As[roa[i]];
    #pragma unroll
    for (int i = 0; i < 4; ++i) bfr[i] = *(const bf16x8*)&Bs[rob[i]];
    #pragma unroll
    for (int mi = 0; mi < 4; ++mi)
      #pragma unroll
      for (int ni = 0; ni < 4; ++ni)
        acc[mi][ni] = __builtin_amdgcn_mfma_f32_16x16x32_bf16(af[mi], bfr[ni], acc[mi][ni], 0, 0, 0);
  }

  // epilogue: D layout col=lane&15, row=(lane>>4)*4+r
  #pragma unroll
  for (int mi = 0; mi < 4; ++mi) {
    #pragma unroll
    for (int r = 0; r < 4; ++r) {
      int row = bm + wm * 64 + mi * 16 + lg * 4 + r;
      #pragma unroll
      for (int ni = 0; ni < 4; ++ni) {
        int col = bn + wn * 64 + ni * 16 + lj;
        if (col < Ncols) C[(size_t)row * Ncols + col] = (OutT)acc[mi][ni][r];
      }
    }
  }
}

// ============ fp32 [K][N] -> bf16 [Npad][K] transpose (weights) ============
__global__ __launch_bounds__(256) void transpose_bf16_kernel(
    const float* __restrict__ B, __bf16* __restrict__ Bt, int K, int N) {
  __shared__ float tile[64][65];
  int n0 = blockIdx.x * 64, k0 = blockIdx.y * 64;
  int tid = threadIdx.x;
  int kr = tid >> 4, nc = (tid & 15) * 4;
  #pragma unroll
  for (int i = 0; i < 4; ++i) {
    int k = kr + i * 16;
    float4 v = make_float4(0.f, 0.f, 0.f, 0.f);
    if (n0 + nc < N) v = *(const float4*)(B + (size_t)(k0 + k) * N + n0 + nc);
    tile[k][nc + 0] = v.x; tile[k][nc + 1] = v.y;
    tile[k][nc + 2] = v.z; tile[k][nc + 3] = v.w;
  }
  __syncthreads();
  int nl = tid >> 4, k4 = (tid & 15) * 4;
  #pragma unroll
  for (int i = 0; i < 4; ++i) {
    int nn = nl + i * 16;
    bf16x4 o;
    o[0] = (__bf16)tile[k4 + 0][nn]; o[1] = (__bf16)tile[k4 + 1][nn];
    o[2] = (__bf16)tile[k4 + 2][nn]; o[3] = (__bf16)tile[k4 + 3][nn];
    *(bf16x4*)(Bt + (size_t)(n0 + nn) * K + k0 + k4) = o;
  }
}

// ============ fp32 -> bf16 elementwise ============
__global__ __launch_bounds__(256) void conv_bf16_kernel(
    const float* __restrict__ in, __bf16* __restrict__ out, int n8) {
  int i = blockIdx.x * 256 + threadIdx.x;
  if (i >= n8) return;
  float4 a = *(const float4*)(in + (size_t)i * 8);
  float4 b = *(const float4*)(in + (size_t)i * 8 + 4);
  bf16x8 v;
  v[0] = (__bf16)a.x; v[1] = (__bf16)a.y; v[2] = (__bf16)a.z; v[3] = (__bf16)a.w;
  v[4] = (__bf16)b.x; v[5] = (__bf16)b.y; v[6] = (__bf16)b.z; v[7] = (__bf16)b.w;
  *(bf16x8*)(out + (size_t)i * 8) = v;
}

// ============ RMSNorm (fp32 in, bf16 out) ============
__global__ __launch_bounds__(256) void rmsnorm_bf16_kernel(
    const float* __restrict__ in, __bf16* __restrict__ out,
    const float* __restrict__ scale, int len, int in_stride) {
  int row = blockIdx.x;
  const float* x = in + (size_t)row * in_stride;
  __bf16* y = out + (size_t)row * len;
  float ss = 0.f;
  for (int i = threadIdx.x; i < len; i += 256) { float v = x[i]; ss += v * v; }
  __shared__ float red[4];
  #pragma unroll
  for (int o = 32; o > 0; o >>= 1) ss += __shfl_down(ss, o, 64);
  int wid = threadIdx.x >> 6, lane = threadIdx.x & 63;
  if (lane == 0) red[wid] = ss;
  __syncthreads();
  if (threadIdx.x == 0) {
    float t = red[0] + red[1] + red[2] + red[3];
    red[0] = 1.0f / sqrtf(t / (float)len + 1e-6f);
  }
  __syncthreads();
  float r = red[0];
  for (int i = threadIdx.x; i < len; i += 256) y[i] = (__bf16)(x[i] * r * scale[i]);
}

// ============ RoPE table ============
struct InvFreq { float f[32]; };
__global__ __launch_bounds__(256) void rope_table_kernel(
    const int* __restrict__ pos, float* __restrict__ cosT, float* __restrict__ sinT,
    InvFreq invf) {
  int idx = blockIdx.x * 256 + threadIdx.x;
  if (idx >= T_ * 32) return;
  int t = idx >> 5, i = idx & 31;
  float fr = (float)pos[t] * invf.f[i];
  cosT[idx] = cosf(fr);
  sinT[idx] = sinf(fr);
}

// ============ RoPE on q (bf16 in place) ============
__global__ __launch_bounds__(256) void rope_q_kernel(
    __bf16* __restrict__ q, const float* __restrict__ cosT, const float* __restrict__ sinT) {
  int idx = blockIdx.x * 256 + threadIdx.x;   // T*NH*32
  if (idx >= T_ * NH_ * 32) return;
  int i = idx & 31;
  int tn = idx >> 5;
  int t = tn >> 5;                            // NH_ == 32
  __bf16* b = q + (size_t)tn * HQK_ + NOPE_;
  float x1 = (float)b[i], x2 = (float)b[i + 32];
  float c = cosT[t * 32 + i], s = sinT[t * 32 + i];
  b[i]      = (__bf16)(x1 * c - x2 * s);
  b[i + 32] = (__bf16)(x1 * s + x2 * c);
}

// ============ RoPE on k (fp32 kv_sa -> bf16 k_rope) ============
__global__ __launch_bounds__(256) void rope_k_kernel(
    const float* __restrict__ kv_sa, const float* __restrict__ cosT,
    const float* __restrict__ sinT, __bf16* __restrict__ k_rope) {
  int idx = blockIdx.x * 256 + threadIdx.x;   // T*32
  if (idx >= T_ * 32) return;
  int t = idx >> 5, i = idx & 31;
  const float* b = kv_sa + (size_t)t * KVD_ + KVL_;
  float x1 = b[i], x2 = b[i + 32];
  float c = cosT[idx], s = sinT[idx];
  k_rope[t * 64 + i]      = (__bf16)(x1 * c - x2 * s);
  k_rope[t * 64 + i + 32] = (__bf16)(x1 * s + x2 * c);
}

// ============ V transpose prep: kv_nopeb[s][n][256] bf16 -> Vt[n][h][s] bf16 ====
__global__ __launch_bounds__(256) void prep_vt_kernel(
    const __bf16* __restrict__ kv_nopeb, __bf16* __restrict__ Vt) {
  __shared__ __bf16 tile[64][136];   // 272B row stride (16B-aligned, banks spread)
  int s0 = blockIdx.x * 64;
  int n = blockIdx.y;
  int tid = threadIdx.x;
  #pragma unroll
  for (int i = 0; i < 4; ++i) {
    int idx = tid + i * 256;          // 1024 tasks: 64 s x 16 chunks
    int s = idx >> 4, c = idx & 15;
    bf16x8 v = *(const bf16x8*)(kv_nopeb + ((size_t)(s0 + s) * NH_ + n) * 256 + NOPE_ + c * 8);
    *(bf16x8*)&tile[s][c * 8] = v;
  }
  __syncthreads();
  #pragma unroll
  for (int i = 0; i < 8; ++i) {
    int idx = tid + i * 256;          // 2048 tasks: 128 h x 16 s4
    int h = idx >> 4, s4 = (idx & 15) * 4;
    bf16x4 v;
    v[0] = tile[s4 + 0][h]; v[1] = tile[s4 + 1][h];
    v[2] = tile[s4 + 2][h]; v[3] = tile[s4 + 3][h];
    *(bf16x4*)(Vt + ((size_t)n * HV_ + h) * T_ + s0 + s4) = v;
  }
}

// ============ MFMA flash attention (all-bf16 inputs) ============
__global__ __launch_bounds__(256) void attn_mfma_kernel(
    const __bf16* __restrict__ q_tnh, const __bf16* __restrict__ kv_nopeb,
    const __bf16* __restrict__ k_rope, const __bf16* __restrict__ Vt,
    __bf16* __restrict__ attn_out, float sm_scale) {
  __shared__ __bf16 Ks[64 * 192];      // elem (s,h): s*192 + ((c^(s&7))<<3) + (h&7), c=h>>3
  __shared__ __bf16 Vs[128 * 64];      // elem (h,s): h*64  + ((c^(h&7))<<3) + (s&7), c=s>>3
  __shared__ __bf16 Ps[4][16 * 64];    // per wave (r,sl): r*64 + ((c^(r&7))<<3) + (sl&7)
  const int tid = threadIdx.x;
  const int lane = tid & 63;
  const int w = tid >> 6;
  const int n = blockIdx.y;
  const int qt = gridDim.x - 1 - blockIdx.x;   // heaviest q-tiles first
  const int t0 = qt * 64;
  const int lg = lane >> 4;
  const int lj = lane & 15;

  // Q fragments, pre-scaled. A layout: row=lane%16, col=kk*32+lg*8+i.
  bf16x8 qf[6];
  {
    int t = t0 + w * 16 + lj;
    const __bf16* qp = q_tnh + ((size_t)t * NH_ + n) * HQK_;
    #pragma unroll
    for (int kk = 0; kk < 6; ++kk) {
      bf16x8 raw = *(const bf16x8*)(qp + kk * 32 + lg * 8);
      bf16x8 v;
      #pragma unroll
      for (int i = 0; i < 8; ++i) v[i] = (__bf16)((float)raw[i] * sm_scale);
      qf[kk] = v;
    }
  }

  f32x4 O[8];
  #pragma unroll
  for (int nb = 0; nb < 8; ++nb) O[nb] = (f32x4){0.f, 0.f, 0.f, 0.f};
  float m_r[4], l_r[4];
  #pragma unroll
  for (int r = 0; r < 4; ++r) { m_r[r] = -1e30f; l_r[r] = 0.f; }

  for (int st = 0; st <= qt; ++st) {
    const int s0 = st * 64;
    __syncthreads();
    // stage K: 64 s x 24 chunks of 8 bf16
    #pragma unroll
    for (int i = 0; i < 6; ++i) {
      int task = tid + i * 256;
      int s = task / 24, c = task % 24;
      const __bf16* src = (c < 16)
          ? (kv_nopeb + ((size_t)(s0 + s) * NH_ + n) * 256 + c * 8)
          : (k_rope + (size_t)(s0 + s) * ROPE_ + (c - 16) * 8);
      bf16x8 v = *(const bf16x8*)src;
      *(bf16x8*)&Ks[s * 192 + ((c ^ (s & 7)) << 3)] = v;
    }
    // stage V^T: 128 h x 8 chunks of 8 bf16
    #pragma unroll
    for (int i = 0; i < 4; ++i) {
      int task = tid + i * 256;
      int h = task >> 3, cs = task & 7;
      bf16x8 v = *(const bf16x8*)(Vt + ((size_t)n * HV_ + h) * T_ + s0 + cs * 8);
      *(bf16x8*)&Vs[h * 64 + ((cs ^ (h & 7)) << 3)] = v;
    }
    __syncthreads();

    // QK^T
    f32x4 S[4];
    #pragma unroll
    for (int sb = 0; sb < 4; ++sb) {
      f32x4 acc = (f32x4){0.f, 0.f, 0.f, 0.f};
      int srow = sb * 16 + lj;
      #pragma unroll
      for (int kk = 0; kk < 6; ++kk) {
        int c = kk * 4 + lg;
        bf16x8 b = *(const bf16x8*)&Ks[srow * 192 + ((c ^ (srow & 7)) << 3)];
        acc = __builtin_amdgcn_mfma_f32_16x16x32_bf16(qf[kk], b, acc, 0, 0, 0);
      }
      S[sb] = acc;
    }
    if (st == qt) {
      #pragma unroll
      for (int sb = 0; sb < 4; ++sb)
        #pragma unroll
        for (int r = 0; r < 4; ++r) {
          int trel = w * 16 + lg * 4 + r;
          int srel = sb * 16 + lj;
          if (srel > trel) S[sb][r] = -1e30f;
        }
    }
    // online softmax
    #pragma unroll
    for (int r = 0; r < 4; ++r) {
      float mx = fmaxf(fmaxf(S[0][r], S[1][r]), fmaxf(S[2][r], S[3][r]));
      mx = fmaxf(mx, __shfl_xor(mx, 1));
      mx = fmaxf(mx, __shfl_xor(mx, 2));
      mx = fmaxf(mx, __shfl_xor(mx, 4));
      mx = fmaxf(mx, __shfl_xor(mx, 8));
      float mnew = fmaxf(m_r[r], mx);
      float corr = __expf(m_r[r] - mnew);
      m_r[r] = mnew;
      float psum = 0.f;
      #pragma unroll
      for (int sb = 0; sb < 4; ++sb) {
        float p = __expf(S[sb][r] - mnew);
        S[sb][r] = p;
        psum += p;
      }
      psum += __shfl_xor(psum, 1);
      psum += __shfl_xor(psum, 2);
      psum += __shfl_xor(psum, 4);
      psum += __shfl_xor(psum, 8);
      l_r[r] = l_r[r] * corr + psum;
      #pragma unroll
      for (int nb = 0; nb < 8; ++nb) O[nb][r] = O[nb][r] * corr;
    }
    // P -> LDS (transpose D-layout -> A-layout)
    #pragma unroll
    for (int sb = 0; sb < 4; ++sb) {
      int sl = sb * 16 + lj;
      int c = sl >> 3;
      #pragma unroll
      for (int r = 0; r < 4; ++r) {
        int rw = lg * 4 + r;
        Ps[w][rw * 64 + ((c ^ (rw & 7)) << 3) + (sl & 7)] = (__bf16)S[sb][r];
      }
    }
    // PV
    #pragma unroll
    for (int kk = 0; kk < 2; ++kk) {
      int ca = kk * 4 + lg;
      bf16x8 pa = *(const bf16x8*)&Ps[w][lj * 64 + ((ca ^ (lj & 7)) << 3)];
      #pragma unroll
      for (int nb = 0; nb < 8; ++nb) {
        int h = nb * 16 + lj;
        bf16x8 bv = *(const bf16x8*)&Vs[h * 64 + ((ca ^ (h & 7)) << 3)];
        O[nb] = __builtin_amdgcn_mfma_f32_16x16x32_bf16(pa, bv, O[nb], 0, 0, 0);
      }
    }
  }
  // epilogue -> bf16
  #pragma unroll
  for (int r = 0; r < 4; ++r) {
    float inv = 1.0f / l_r[r];
    int t = t0 + w * 16 + lg * 4 + r;
    __bf16* dst = attn_out + ((size_t)t * NH_ + n) * HV_;
    #pragma unroll
    for (int nb = 0; nb < 8; ++nb) dst[nb * 16 + lj] = (__bf16)(O[nb][r] * inv);
  }
}

// ================= host side =================
static void compute_inv_freq(float* out) {
  const double theta = 10000.0, factor = 40.0;
  const double PI = 3.14159265358979323846;
  const int rot = ROPE_;
  double low_d  = rot * log(4096.0 / (32.0 * 2.0 * PI)) / (2.0 * log(theta));
  double high_d = rot * log(4096.0 / ( 1.0 * 2.0 * PI)) / (2.0 * log(theta));
  double low = floor(low_d);  if (low < 0) low = 0;
  double high = ceil(high_d); if (high > rot - 1) high = rot - 1;
  for (int i = 0; i < 32; ++i) {
    double pf = pow(theta, (2.0 * i) / (double)rot);
    double inv_extra = 1.0 / pf;
    double inv_inter = 1.0 / (factor * pf);
    double ramp = ((double)i - low) / fmax(high - low, 0.001);
    ramp = fmin(fmax(ramp, 0.0), 1.0);
    double mask = 1.0 - ramp;
    out[i] = (float)(inv_inter * (1.0 - mask) + inv_extra * mask);
  }
}

extern "C" void kernel_launch(void* const* d_in, const int* in_sizes, int n_in,
                              void* d_out, int out_size, void* d_ws, size_t ws_size,
                              hipStream_t stream) {
  const float* x            = (const float*)d_in[0];
  const int*   positions    = (const int*)d_in[1];
  const float* w_q_down     = (const float*)d_in[2];
  const float* q_norm_scale = (const float*)d_in[3];
  const float* w_q_up       = (const float*)d_in[4];
  const float* w_kv_down    = (const float*)d_in[5];
  const float* kv_norm_scale= (const float*)d_in[6];
  const float* w_kv_up      = (const float*)d_in[7];
  const float* w_o          = (const float*)d_in[8];
  float* out = (float*)d_out;

  // ---- workspace layout (float offsets), liveness-aliased; total 36,175,872 fl
  //      (144.7 MB, < 173.5 MB proven in round 1) ----
  float* ws = (float*)d_ws;
  float*  cosT     = ws;                           // 65,536           dead@rope_k
  float*  sinT     = ws + 65536;                   // 65,536           dead@rope_k
  float*  kv_sa    = ws + 131072;                  // 1,179,648 fp32   dead@rope_k
  float*  q_ta     = ws + 1310720;                 // 3,145,728 fp32   dead@rmsnorm_q
  __bf16* xb       = (__bf16*)(ws + 4456448);      // 8,388,608 bf16   dead@gemm kv_down
  __bf16* Bt_qd    = (__bf16*)(ws + 8650752);      // 6,291,456 bf16   dead@gemm q_down
  __bf16* Bt_qu    = (__bf16*)(ws + 11796480);     // 9,437,184 bf16   dead@gemm q_up
  __bf16* Bt_kvd   = (__bf16*)(ws + 16515072);     // 2,621,440 bf16 (640 pad) dead@gemm kv_down
  __bf16* Bt_kvu   = (__bf16*)(ws + 17825792);     // 4,194,304 bf16   dead@gemm kv_up
  __bf16* q_tab    = (__bf16*)(ws + 19922944);     // 3,145,728 bf16   dead@gemm q_up
  __bf16* q_tnhb   = (__bf16*)(ws + 21495808);     // 12,582,912 bf16  dead@attn
  __bf16* kv_nopeb = (__bf16*)(ws + 27787264);     // 16,777,216 bf16  dead@attn
  // aliases (written only after the underlying buffers are dead):
  __bf16* Vt       = (__bf16*)ws;                  // 8,388,608 bf16  @prep_vt  (over cosT..q_ta)
  __bf16* attn_ob  = (__bf16*)(ws + 4194304);      // 8,388,608 bf16  @attn     (over q_ta tail+xb)
  __bf16* kv_latb  = (__bf16*)(ws + 8650752);      // 1,048,576 bf16  @rmsnorm_kv (over Bt_qd)
  __bf16* k_ropeb  = (__bf16*)(ws + 9175040);      // 131,072 bf16    @rope_k     (over Bt_qd)
  __bf16* Bt_o     = (__bf16*)(ws + 21495808);     // 16,777,216 bf16 @post-attn  (over q_tnhb+kv_nopeb)
  (void)ws_size; (void)n_in; (void)in_sizes; (void)out_size;

  InvFreq invf;
  compute_inv_freq(invf.f);
  double ym = 0.1 * log(40.0) + 1.0;
  float sm_scale = (float)(ym * ym / sqrt((double)HQK_));

  // rope tables + input conversions
  rope_table_kernel<<<(T_ * 32 + 255) / 256, 256, 0, stream>>>(positions, cosT, sinT, invf);
  conv_bf16_kernel<<<T_ * D_ / 8 / 256, 256, 0, stream>>>(x, xb, T_ * D_ / 8);
  transpose_bf16_kernel<<<dim3(QL_ / 64, D_ / 64), 256, 0, stream>>>(w_q_down, Bt_qd, D_, QL_);
  transpose_bf16_kernel<<<dim3(NH_ * HQK_ / 64, QL_ / 64), 256, 0, stream>>>(w_q_up, Bt_qu, QL_, NH_ * HQK_);
  transpose_bf16_kernel<<<dim3(640 / 64, D_ / 64), 256, 0, stream>>>(w_kv_down, Bt_kvd, D_, KVD_);
  transpose_bf16_kernel<<<dim3(NH_ * 256 / 64, KVL_ / 64), 256, 0, stream>>>(w_kv_up, Bt_kvu, KVL_, NH_ * 256);

  // q path
  mfma_gemm_kernel<float><<<dim3(QL_ / 128, T_ / 128), 256, 0, stream>>>(xb, Bt_qd, q_ta, T_, QL_, D_);
  rmsnorm_bf16_kernel<<<T_, 256, 0, stream>>>(q_ta, q_tab, q_norm_scale, QL_, QL_);
  mfma_gemm_kernel<__bf16><<<dim3(NH_ * HQK_ / 128, T_ / 128), 256, 0, stream>>>(q_tab, Bt_qu, q_tnhb, T_, NH_ * HQK_, QL_);
  rope_q_kernel<<<(T_ * NH_ * 32 + 255) / 256, 256, 0, stream>>>(q_tnhb, cosT, sinT);

  // kv path
  mfma_gemm_kernel<float><<<dim3(640 / 128, T_ / 128), 256, 0, stream>>>(xb, Bt_kvd, kv_sa, T_, KVD_, D_);
  rmsnorm_bf16_kernel<<<T_, 256, 0, stream>>>(kv_sa, kv_latb, kv_norm_scale, KVL_, KVD_);
  rope_k_kernel<<<(T_ * 32 + 255) / 256, 256, 0, stream>>>(kv_sa, cosT, sinT, k_ropeb);
  mfma_gemm_kernel<__bf16><<<dim3(NH_ * 256 / 128, T_ / 128), 256, 0, stream>>>(kv_latb, Bt_kvu, kv_nopeb, T_, NH_ * 256, KVL_);

  // attention
  prep_vt_kernel<<<dim3(T_ / 64, NH_), 256, 0, stream>>>(kv_nopeb, Vt);
  attn_mfma_kernel<<<dim3(T_ / 64, NH_), 256, 0, stream>>>(q_tnhb, kv_nopeb, k_ropeb, Vt, attn_ob, sm_scale);

  // output projection (w_o transpose deferred until q_tnhb/kv_nopeb are dead)
  transpose_bf16_kernel<<<dim3(D_ / 64, NH_ * HV_ / 64), 256, 0, stream>>>(w_o, Bt_o, NH_ * HV_, D_);
  mfma_gemm_kernel<float><<<dim3(D_ / 128, T_ / 128), 256, 0, stream>>>(attn_ob, Bt_o, out, T_, D_, NH_ * HV_);
}